// Round 8
// baseline (395.418 us; speedup 1.0000x reference)
//
#include <hip/hip_runtime.h>
#include <hip/hip_bf16.h>

#define N_NODES 50000
#define N_EDGES 600000
#define FEA_DIM 128
#define H_DIM 256
#define N_LAYER 3
#define N_GRAPHS 256
#define LABEL_DIM 2

#define SCAN_NB ((N_NODES + 255) / 256)        // 196
#define GEMM_NB ((N_NODES + 63) / 64)          // 782
#define EDGE_NB ((N_EDGES + 255) / 256)        // 2344 (256-thr kernels)
#define FILL_NB ((N_EDGES + 255) / 256)        // 2344 fill blocks (128 thr x 2 edges)
#define AGG_NB (N_NODES)                       // 50000 one-wave blocks: 2 nodes x 1 half

// ---------------- CSR: degree count ----------------

__global__ __launch_bounds__(256) void k_count(const int* __restrict__ dst, int* __restrict__ counts) {
    int e = blockIdx.x * 256 + threadIdx.x;
    if (e < N_EDGES) atomicAdd(&counts[dst[e]], 1);
}

// ---------------- GEMM body: BM=64, BK=32, 128 thr, 8x8, reg-double-buffered
// Round-7 8x8 register tile (64 fmac per 64 B LDS) + T14 issue-early/
// write-late staging: tile kt+1's global loads are issued right after the
// barrier, before computing kt from LDS — HBM/L2 latency hides under the
// 4096-cyc fmac phase instead of draining at the barrier (VALUBusy was 22%).
// VGPR ~136 keeps 3 waves/SIMD (512/136); LDS unchanged -> same occupancy.
// Per-output fmac chain unchanged: k ascending 0..127 -> bitwise identical.

__device__ __forceinline__ void gemm_body(const float* __restrict__ X, const float* __restrict__ W,
                                          float* __restrict__ H, int M, int tile) {
    __shared__ float a_s[32][68];
    __shared__ float b_s[32][128];
    const int tid = threadIdx.x;
    const int row_g = tid >> 4;    // 0..7
    const int col_g = tid & 15;    // 0..15
    const int row_base = tile * 64;
    float acc[8][8] = {};
    float4 ar[4], br[8];

    // prologue: stage tile kt=0 into registers
#pragma unroll
    for (int j = 0; j < 4; ++j) {
        int id = tid + j * 128;
        int m = id >> 3, kq = (id & 7) << 2;
        int gr = row_base + m;
        ar[j] = (gr < M) ? *(const float4*)(X + gr * 128 + kq) : make_float4(0.f, 0.f, 0.f, 0.f);
    }
#pragma unroll
    for (int j = 0; j < 8; ++j) {
        int id = tid + j * 128;
        int k = id >> 5, n = (id & 31) << 2;
        br[j] = *(const float4*)(W + k * 128 + n);
    }

    for (int kt = 0; kt < 4; ++kt) {
        // write staged regs -> LDS
#pragma unroll
        for (int j = 0; j < 4; ++j) {
            int id = tid + j * 128;
            int m = id >> 3, kq = (id & 7) << 2;
            a_s[kq + 0][m] = ar[j].x; a_s[kq + 1][m] = ar[j].y;
            a_s[kq + 2][m] = ar[j].z; a_s[kq + 3][m] = ar[j].w;
        }
#pragma unroll
        for (int j = 0; j < 8; ++j) {
            int id = tid + j * 128;
            int k = id >> 5, n = (id & 31) << 2;
            *(float4*)(&b_s[k][n]) = br[j];
        }
        __syncthreads();
        // issue next tile's global loads now — latency hides under compute
        if (kt < 3) {
            const int k0n = (kt + 1) * 32;
#pragma unroll
            for (int j = 0; j < 4; ++j) {
                int id = tid + j * 128;
                int m = id >> 3, kq = (id & 7) << 2;
                int gr = row_base + m;
                ar[j] = (gr < M) ? *(const float4*)(X + gr * 128 + k0n + kq) : make_float4(0.f, 0.f, 0.f, 0.f);
            }
#pragma unroll
            for (int j = 0; j < 8; ++j) {
                int id = tid + j * 128;
                int k = id >> 5, n = (id & 31) << 2;
                br[j] = *(const float4*)(W + (k0n + k) * 128 + n);
            }
        }
        // compute kt from LDS
#pragma unroll 4
        for (int k = 0; k < 32; ++k) {
            float4 a0 = *(const float4*)(&a_s[k][row_g * 8]);
            float4 a1 = *(const float4*)(&a_s[k][row_g * 8 + 4]);
            float4 b0 = *(const float4*)(&b_s[k][col_g * 4]);
            float4 b1 = *(const float4*)(&b_s[k][64 + col_g * 4]);
            float av[8] = {a0.x, a0.y, a0.z, a0.w, a1.x, a1.y, a1.z, a1.w};
            float bv[8] = {b0.x, b0.y, b0.z, b0.w, b1.x, b1.y, b1.z, b1.w};
#pragma unroll
            for (int i = 0; i < 8; ++i)
#pragma unroll
                for (int jj = 0; jj < 8; ++jj) acc[i][jj] += av[i] * bv[jj];
        }
        __syncthreads();   // all waves done reading before next overwrite
    }
#pragma unroll
    for (int i = 0; i < 8; ++i) {
        int gr = row_base + row_g * 8 + i;
        if (gr < M) {
            float4 o0 = {acc[i][0], acc[i][1], acc[i][2], acc[i][3]};
            float4 o1 = {acc[i][4], acc[i][5], acc[i][6], acc[i][7]};
            *(float4*)(H + gr * 128 + col_g * 4) = o0;
            *(float4*)(H + gr * 128 + 64 + col_g * 4) = o1;
        }
    }
}

__global__ __launch_bounds__(128) void k_gemm(const float* __restrict__ X, const float* __restrict__ W,
                                              float* __restrict__ H, int M) {
    gemm_body(X, W, H, M, blockIdx.x);
}

// Fused: blocks [0, GEMM_NB) run GEMM layer-0 tiles; blocks [GEMM_NB, ...) do
// CSR fill at 2 edges/thread (256 edges/block) — restores round-6's
// edges-in-flight per CU under the 25 KB LDS block-cap (6 blocks/CU).
__global__ __launch_bounds__(128) void k_gemm0_fill(const float* __restrict__ X, const float* __restrict__ W,
                                                    float* __restrict__ H,
                                                    const int* __restrict__ src, const int* __restrict__ dst,
                                                    const int* __restrict__ row_ptr, int* __restrict__ cursor,
                                                    int* __restrict__ col) {
    if (blockIdx.x < GEMM_NB) {
        gemm_body(X, W, H, N_NODES, blockIdx.x);
    } else {
        int base = (blockIdx.x - GEMM_NB) * 256 + threadIdx.x;
#pragma unroll
        for (int q = 0; q < 2; ++q) {
            int e = base + q * 128;
            if (e < N_EDGES) {
                int s = src[e], d = dst[e];
                int p = row_ptr[d] + atomicAdd(&cursor[d], 1);
                col[p] = s;
            }
        }
    }
}

// ---------------- CSR build (scan phases) ----------------

__global__ __launch_bounds__(256) void k_partial(const int* __restrict__ counts, int* __restrict__ partial) {
    int g = blockIdx.x * 256 + threadIdx.x;
    int v = (g < N_NODES) ? counts[g] : 0;
#pragma unroll
    for (int off = 32; off > 0; off >>= 1) v += __shfl_down(v, off);
    __shared__ int ws[4];
    int lane = threadIdx.x & 63, wid = threadIdx.x >> 6;
    if (lane == 0) ws[wid] = v;
    __syncthreads();
    if (threadIdx.x == 0) partial[blockIdx.x] = ws[0] + ws[1] + ws[2] + ws[3];
}

__global__ __launch_bounds__(256) void k_rowptr(const int* __restrict__ counts, const int* __restrict__ partial,
                                                int* __restrict__ row_ptr, float* __restrict__ dinv,
                                                int* __restrict__ cursor) {
    __shared__ int sp[256];
    __shared__ int s[256];
    int tid = threadIdx.x;
    sp[tid] = (tid < SCAN_NB) ? partial[tid] : 0;
    __syncthreads();
#pragma unroll
    for (int off = 1; off < 256; off <<= 1) {
        int t = (tid >= off) ? sp[tid - off] : 0;
        __syncthreads();
        sp[tid] += t;
        __syncthreads();
    }
    int block_off = (blockIdx.x == 0) ? 0 : sp[blockIdx.x - 1];

    int g = blockIdx.x * 256 + tid;
    int c = (g < N_NODES) ? counts[g] : 0;
    s[tid] = c;
    __syncthreads();
#pragma unroll
    for (int off = 1; off < 256; off <<= 1) {
        int t = (tid >= off) ? s[tid - off] : 0;
        __syncthreads();
        s[tid] += t;
        __syncthreads();
    }
    if (g < N_NODES) {
        row_ptr[g] = block_off + s[tid] - c;            // exclusive
        dinv[g] = rsqrtf((float)c + 1.0f);              // +1 = self loop
        cursor[g] = 0;
    }
    if (blockIdx.x == 0 && tid == 0) row_ptr[N_NODES] = sp[SCAN_NB - 1];
}

// ---------------- Aggregation: XCD-aware feature split, 1-wave blocks -------
// Round-6 proven (best measured): feature-half = blockIdx&1 (XCD parity),
// unit = 32 lanes = one node's 64-feature half (float2/lane), 1-wave blocks
// (scheduling granularity), batch-of-8 gather prefetch. Per-output fmac
// order: self-loop, then CSR edges strictly ascending — bitwise identical.

__global__ __launch_bounds__(64) void k_agg(const float* __restrict__ H, const float* __restrict__ bgl,
                                            const int* __restrict__ row_ptr, const int* __restrict__ col,
                                            const float* __restrict__ dinv,
                                            float* __restrict__ Xo) {
    const int b = blockIdx.x;
    const int half = b & 1;                       // feature half (XCD parity)
    const int unit = threadIdx.x >> 5;            // 0..1
    const int fl = threadIdx.x & 31;
    const int i = (b >> 1) * 2 + unit;            // node id (50000 = 25000*2, no tail)
    const int fo = half * 32 + fl;                // float2 index within the row
    const float2* H2 = (const float2*)H;
    const float di = dinv[i];
    float2 h = H2[(size_t)i * 64 + fo];
    float2 acc;
    acc.x = h.x * di * di;   // self-loop first
    acc.y = h.y * di * di;
    const int p0 = row_ptr[i], p1 = row_ptr[i + 1];
    for (int base = p0; base < p1; base += 32) {
        int m = p1 - base; if (m > 32) m = 32;
        int sc = 0; float wc = 0.f;
        if (fl < m) { sc = col[base + fl]; wc = dinv[sc] * di; }
        for (int j = 0; j < m; j += 8) {
            int cnt = m - j; if (cnt > 8) cnt = 8;
            float2 hbuf[8]; float wbuf[8];
#pragma unroll
            for (int t = 0; t < 8; ++t) {
                if (t < cnt) {
                    int s = __shfl(sc, j + t, 32);
                    wbuf[t] = __shfl(wc, j + t, 32);
                    hbuf[t] = H2[(size_t)s * 64 + fo];
                }
            }
#pragma unroll
            for (int t = 0; t < 8; ++t) {
                if (t < cnt) {
                    acc.x += hbuf[t].x * wbuf[t];
                    acc.y += hbuf[t].y * wbuf[t];
                }
            }
        }
    }
    float2 bb = ((const float2*)bgl)[fo];
    float2 o;
    o.x = fmaxf(acc.x + bb.x, 0.f);
    o.y = fmaxf(acc.y + bb.y, 0.f);
    ((float2*)Xo)[(size_t)i * 64 + fo] = o;
}

// ---------------- Fused mean pool + MLP head ----------------

__global__ __launch_bounds__(256) void k_poolmlp(const float* __restrict__ X, const int* __restrict__ batch,
                                                 const float* __restrict__ w1, const float* __restrict__ b1,
                                                 const float* __restrict__ w2, const float* __restrict__ b2,
                                                 float* __restrict__ out) {
    __shared__ int s_lo, s_hi;
    __shared__ float red[256];
    __shared__ float xs[128];
    __shared__ float hs[256];
    int g = blockIdx.x, tid = threadIdx.x;
    if (tid == 0) {
        int lo = 0, hi = N_NODES;
        while (lo < hi) { int mid = (lo + hi) >> 1; if (batch[mid] < g) lo = mid + 1; else hi = mid; }
        s_lo = lo;
        int lo2 = lo, hi2 = N_NODES;
        while (lo2 < hi2) { int mid = (lo2 + hi2) >> 1; if (batch[mid] < g + 1) lo2 = mid + 1; else hi2 = mid; }
        s_hi = lo2;
    }
    __syncthreads();
    int lo = s_lo, hi = s_hi;
    int f = tid & 127, half = tid >> 7;
    float acc = 0.f;
    for (int r = lo + half; r < hi; r += 2) acc += X[r * 128 + f];
    red[tid] = acc;
    __syncthreads();
    if (tid < 128) {
        int cnt = hi - lo;
        xs[tid] = (red[tid] + red[tid + 128]) / (float)(cnt > 0 ? cnt : 1);
    }
    __syncthreads();
    float a1 = b1[tid];
#pragma unroll 8
    for (int k = 0; k < 128; ++k) a1 += xs[k] * w1[k * H_DIM + tid];
    hs[tid] = fmaxf(a1, 0.f);
    __syncthreads();
    int j = tid >> 7, t2 = tid & 127;
    float p = hs[t2] * w2[t2 * LABEL_DIM + j] + hs[t2 + 128] * w2[(t2 + 128) * LABEL_DIM + j];
    red[tid] = p;
    __syncthreads();
    for (int s2 = 64; s2 > 0; s2 >>= 1) {
        if (t2 < s2) red[tid] += red[tid + s2];
        __syncthreads();
    }
    if (t2 == 0) out[g * LABEL_DIM + j] = red[tid] + b2[j];
}

// ---------------- launch ----------------

extern "C" void kernel_launch(void* const* d_in, const int* in_sizes, int n_in,
                              void* d_out, int out_size, void* d_ws, size_t ws_size,
                              hipStream_t stream) {
    const float* x   = (const float*)d_in[0];
    const float* Wg  = (const float*)d_in[1];
    const float* bg  = (const float*)d_in[2];
    const float* w1  = (const float*)d_in[3];
    const float* b1  = (const float*)d_in[4];
    const float* w2  = (const float*)d_in[5];
    const float* b2  = (const float*)d_in[6];
    const int* eidx  = (const int*)d_in[7];
    const int* batch = (const int*)d_in[8];
    float* out = (float*)d_out;

    const int* src = eidx;
    const int* dst = eidx + N_EDGES;

    char* ws = (char*)d_ws;
    size_t off = 0;
    float* A = (float*)(ws + off); off += (size_t)N_NODES * FEA_DIM * 4;
    float* B = (float*)(ws + off); off += (size_t)N_NODES * FEA_DIM * 4;
    int*   col = (int*)(ws + off); off += (size_t)N_EDGES * 4;
    int*   row_ptr = (int*)(ws + off); off += 200704;
    int*   cursor  = (int*)(ws + off); off += 200704;
    int*   counts  = (int*)(ws + off); off += 200704;
    float* dinv    = (float*)(ws + off); off += 200704;
    int*   partial = (int*)(ws + off); off += 4096;

    hipMemsetAsync(counts, 0, 200704, stream);
    k_count<<<EDGE_NB, 256, 0, stream>>>(dst, counts);
    k_partial<<<SCAN_NB, 256, 0, stream>>>(counts, partial);
    k_rowptr<<<SCAN_NB, 256, 0, stream>>>(counts, partial, row_ptr, dinv, cursor);
    // gemm layer-0 fused with CSR fill (independent works)
    k_gemm0_fill<<<GEMM_NB + FILL_NB, 128, 0, stream>>>(x, Wg, B, src, dst, row_ptr, cursor, col);

    k_agg<<<AGG_NB, 64, 0, stream>>>(B, bg + 0 * FEA_DIM, row_ptr, col, dinv, A);
    for (int l = 1; l < N_LAYER; ++l) {
        k_gemm<<<GEMM_NB, 128, 0, stream>>>(A, Wg + (size_t)l * FEA_DIM * FEA_DIM, B, N_NODES);
        k_agg<<<AGG_NB, 64, 0, stream>>>(B, bg + (size_t)l * FEA_DIM, row_ptr, col, dinv, A);
    }
    k_poolmlp<<<N_GRAPHS, 256, 0, stream>>>(A, batch, w1, b1, w2, b2, out);
}

// Round 9
// 392.161 us; speedup vs baseline: 1.0083x; 1.0083x over previous
//
#include <hip/hip_runtime.h>
#include <hip/hip_bf16.h>

#define N_NODES 50000
#define N_EDGES 600000
#define FEA_DIM 128
#define H_DIM 256
#define N_LAYER 3
#define N_GRAPHS 256
#define LABEL_DIM 2

#define SCAN_NB ((N_NODES + 255) / 256)        // 196
#define GEMM_NB ((N_NODES + 63) / 64)          // 782
#define EDGE_NB ((N_EDGES + 255) / 256)        // 2344 (256-thr kernels)
#define AGG_NB (N_NODES)                       // 50000 one-wave blocks: 2 nodes x 1 half

// ---------------- CSR: degree count ----------------

__global__ __launch_bounds__(256) void k_count(const int* __restrict__ dst, int* __restrict__ counts) {
    int e = blockIdx.x * 256 + threadIdx.x;
    if (e < N_EDGES) atomicAdd(&counts[dst[e]], 1);
}

// ---------------- GEMM body A (round-6 proven): BM=64, BK=32, 256 thr, 4x8 --
// Used ONLY in the fused layer-0 kernel: 256-thr blocks keep the co-scheduled
// CSR-fill blocks at full concurrency (round-6 config measured 43.6 us with
// fill fully hidden; every 128-thr fused variant exposed the fill).
// Per-output fmac order: k ascending 0..127.

__device__ __forceinline__ void gemm_body256(const float* __restrict__ X, const float* __restrict__ W,
                                             float* __restrict__ H, int M, int tile) {
    __shared__ float a_s[32][68];
    __shared__ float b_s[32][128];
    const int tid = threadIdx.x;
    const int row_g = tid >> 4;
    const int col_g = tid & 15;
    const int row_base = tile * 64;
    float acc[4][8] = {};

    for (int kt = 0; kt < 4; ++kt) {
        const int k0 = kt * 32;
#pragma unroll
        for (int j = 0; j < 2; ++j) {
            int id = tid + j * 256;
            int m = id >> 3;
            int kq = (id & 7) << 2;
            float4 v = make_float4(0.f, 0.f, 0.f, 0.f);
            int gr = row_base + m;
            if (gr < M) v = *(const float4*)(X + gr * 128 + k0 + kq);
            a_s[kq + 0][m] = v.x; a_s[kq + 1][m] = v.y;
            a_s[kq + 2][m] = v.z; a_s[kq + 3][m] = v.w;
        }
#pragma unroll
        for (int j = 0; j < 4; ++j) {
            int id = tid + j * 256;
            int k = id >> 5;
            int n = (id & 31) << 2;
            *(float4*)(&b_s[k][n]) = *(const float4*)(W + (k0 + k) * 128 + n);
        }
        __syncthreads();
#pragma unroll 8
        for (int k = 0; k < 32; ++k) {
            float4 a0 = *(const float4*)(&a_s[k][row_g * 4]);
            float4 b0 = *(const float4*)(&b_s[k][col_g * 4]);
            float4 b1 = *(const float4*)(&b_s[k][64 + col_g * 4]);
            float av[4] = {a0.x, a0.y, a0.z, a0.w};
            float bv[8] = {b0.x, b0.y, b0.z, b0.w, b1.x, b1.y, b1.z, b1.w};
#pragma unroll
            for (int i = 0; i < 4; ++i)
#pragma unroll
                for (int jj = 0; jj < 8; ++jj) acc[i][jj] += av[i] * bv[jj];
        }
        __syncthreads();
    }
#pragma unroll
    for (int i = 0; i < 4; ++i) {
        int gr = row_base + row_g * 4 + i;
        if (gr < M) {
            float4 o0 = {acc[i][0], acc[i][1], acc[i][2], acc[i][3]};
            float4 o1 = {acc[i][4], acc[i][5], acc[i][6], acc[i][7]};
            *(float4*)(H + gr * 128 + col_g * 4) = o0;
            *(float4*)(H + gr * 128 + 64 + col_g * 4) = o1;
        }
    }
}

// Fused: blocks [0, GEMM_NB) run GEMM layer-0 tiles; blocks [GEMM_NB, ...) do
// CSR fill (1 edge/thread, 256 thr — round-6 proven; fill hides under GEMM).
__global__ __launch_bounds__(256) void k_gemm0_fill(const float* __restrict__ X, const float* __restrict__ W,
                                                    float* __restrict__ H,
                                                    const int* __restrict__ src, const int* __restrict__ dst,
                                                    const int* __restrict__ row_ptr, int* __restrict__ cursor,
                                                    int* __restrict__ col) {
    if (blockIdx.x < GEMM_NB) {
        gemm_body256(X, W, H, N_NODES, blockIdx.x);
    } else {
        int e = (blockIdx.x - GEMM_NB) * 256 + threadIdx.x;
        if (e < N_EDGES) {
            int s = src[e], d = dst[e];
            int p = row_ptr[d] + atomicAdd(&cursor[d], 1);
            col[p] = s;
        }
    }
}

// ---------------- GEMM body B: BM=64, BK=32, 128 thr, 8x8, reg-dbuf --------
// Round-8 structure with the spill fixed: __launch_bounds__(128, 2) raises
// the per-wave VGPR cap to 256, so acc(64)+ar(16)+br(32)+addr (~140) stays in
// registers (round 8: compiler kept 88 and spilled ar/br -> +46 MB scratch
// traffic). LDS (25 KB, 6 blocks/CU = 12 waves/CU) remains the binding
// occupancy cap at either VGPR count — zero occupancy cost.
// T14 issue-early: next tile's global loads issue right after the barrier,
// hiding HBM/L2 latency under the fmac phase. Per-output fmac chain: k
// ascending 0..127 — bitwise identical.

__global__ __launch_bounds__(128, 2) void k_gemm(const float* __restrict__ X, const float* __restrict__ W,
                                                 float* __restrict__ H, int M) {
    __shared__ float a_s[32][68];
    __shared__ float b_s[32][128];
    const int tid = threadIdx.x;
    const int row_g = tid >> 4;    // 0..7
    const int col_g = tid & 15;    // 0..15
    const int row_base = blockIdx.x * 64;
    float acc[8][8] = {};
    float4 ar[4], br[8];

    // prologue: stage tile kt=0 into registers
#pragma unroll
    for (int j = 0; j < 4; ++j) {
        int id = tid + j * 128;
        int m = id >> 3, kq = (id & 7) << 2;
        int gr = row_base + m;
        ar[j] = (gr < M) ? *(const float4*)(X + gr * 128 + kq) : make_float4(0.f, 0.f, 0.f, 0.f);
    }
#pragma unroll
    for (int j = 0; j < 8; ++j) {
        int id = tid + j * 128;
        int k = id >> 5, n = (id & 31) << 2;
        br[j] = *(const float4*)(W + k * 128 + n);
    }

    for (int kt = 0; kt < 4; ++kt) {
        // write staged regs -> LDS
#pragma unroll
        for (int j = 0; j < 4; ++j) {
            int id = tid + j * 128;
            int m = id >> 3, kq = (id & 7) << 2;
            a_s[kq + 0][m] = ar[j].x; a_s[kq + 1][m] = ar[j].y;
            a_s[kq + 2][m] = ar[j].z; a_s[kq + 3][m] = ar[j].w;
        }
#pragma unroll
        for (int j = 0; j < 8; ++j) {
            int id = tid + j * 128;
            int k = id >> 5, n = (id & 31) << 2;
            *(float4*)(&b_s[k][n]) = br[j];
        }
        __syncthreads();
        // issue next tile's global loads now — latency hides under compute
        if (kt < 3) {
            const int k0n = (kt + 1) * 32;
#pragma unroll
            for (int j = 0; j < 4; ++j) {
                int id = tid + j * 128;
                int m = id >> 3, kq = (id & 7) << 2;
                int gr = row_base + m;
                ar[j] = (gr < M) ? *(const float4*)(X + gr * 128 + k0n + kq) : make_float4(0.f, 0.f, 0.f, 0.f);
            }
#pragma unroll
            for (int j = 0; j < 8; ++j) {
                int id = tid + j * 128;
                int k = id >> 5, n = (id & 31) << 2;
                br[j] = *(const float4*)(W + (k0n + k) * 128 + n);
            }
        }
        // compute kt from LDS
#pragma unroll 4
        for (int k = 0; k < 32; ++k) {
            float4 a0 = *(const float4*)(&a_s[k][row_g * 8]);
            float4 a1 = *(const float4*)(&a_s[k][row_g * 8 + 4]);
            float4 b0 = *(const float4*)(&b_s[k][col_g * 4]);
            float4 b1 = *(const float4*)(&b_s[k][64 + col_g * 4]);
            float av[8] = {a0.x, a0.y, a0.z, a0.w, a1.x, a1.y, a1.z, a1.w};
            float bv[8] = {b0.x, b0.y, b0.z, b0.w, b1.x, b1.y, b1.z, b1.w};
#pragma unroll
            for (int i = 0; i < 8; ++i)
#pragma unroll
                for (int jj = 0; jj < 8; ++jj) acc[i][jj] += av[i] * bv[jj];
        }
        __syncthreads();   // all waves done reading before next overwrite
    }
#pragma unroll
    for (int i = 0; i < 8; ++i) {
        int gr = row_base + row_g * 8 + i;
        if (gr < M) {
            float4 o0 = {acc[i][0], acc[i][1], acc[i][2], acc[i][3]};
            float4 o1 = {acc[i][4], acc[i][5], acc[i][6], acc[i][7]};
            *(float4*)(H + gr * 128 + col_g * 4) = o0;
            *(float4*)(H + gr * 128 + 64 + col_g * 4) = o1;
        }
    }
}

// ---------------- CSR build (scan phases) ----------------

__global__ __launch_bounds__(256) void k_partial(const int* __restrict__ counts, int* __restrict__ partial) {
    int g = blockIdx.x * 256 + threadIdx.x;
    int v = (g < N_NODES) ? counts[g] : 0;
#pragma unroll
    for (int off = 32; off > 0; off >>= 1) v += __shfl_down(v, off);
    __shared__ int ws[4];
    int lane = threadIdx.x & 63, wid = threadIdx.x >> 6;
    if (lane == 0) ws[wid] = v;
    __syncthreads();
    if (threadIdx.x == 0) partial[blockIdx.x] = ws[0] + ws[1] + ws[2] + ws[3];
}

__global__ __launch_bounds__(256) void k_rowptr(const int* __restrict__ counts, const int* __restrict__ partial,
                                                int* __restrict__ row_ptr, float* __restrict__ dinv,
                                                int* __restrict__ cursor) {
    __shared__ int sp[256];
    __shared__ int s[256];
    int tid = threadIdx.x;
    sp[tid] = (tid < SCAN_NB) ? partial[tid] : 0;
    __syncthreads();
#pragma unroll
    for (int off = 1; off < 256; off <<= 1) {
        int t = (tid >= off) ? sp[tid - off] : 0;
        __syncthreads();
        sp[tid] += t;
        __syncthreads();
    }
    int block_off = (blockIdx.x == 0) ? 0 : sp[blockIdx.x - 1];

    int g = blockIdx.x * 256 + tid;
    int c = (g < N_NODES) ? counts[g] : 0;
    s[tid] = c;
    __syncthreads();
#pragma unroll
    for (int off = 1; off < 256; off <<= 1) {
        int t = (tid >= off) ? s[tid - off] : 0;
        __syncthreads();
        s[tid] += t;
        __syncthreads();
    }
    if (g < N_NODES) {
        row_ptr[g] = block_off + s[tid] - c;            // exclusive
        dinv[g] = rsqrtf((float)c + 1.0f);              // +1 = self loop
        cursor[g] = 0;
    }
    if (blockIdx.x == 0 && tid == 0) row_ptr[N_NODES] = sp[SCAN_NB - 1];
}

// ---------------- Aggregation: XCD-aware feature split, 1-wave blocks -------
// Round-6 proven (best measured): feature-half = blockIdx&1 (XCD parity),
// unit = 32 lanes = one node's 64-feature half (float2/lane), 1-wave blocks
// (scheduling granularity), batch-of-8 gather prefetch. Per-output fmac
// order: self-loop, then CSR edges strictly ascending — bitwise identical.

__global__ __launch_bounds__(64) void k_agg(const float* __restrict__ H, const float* __restrict__ bgl,
                                            const int* __restrict__ row_ptr, const int* __restrict__ col,
                                            const float* __restrict__ dinv,
                                            float* __restrict__ Xo) {
    const int b = blockIdx.x;
    const int half = b & 1;                       // feature half (XCD parity)
    const int unit = threadIdx.x >> 5;            // 0..1
    const int fl = threadIdx.x & 31;
    const int i = (b >> 1) * 2 + unit;            // node id (50000 = 25000*2, no tail)
    const int fo = half * 32 + fl;                // float2 index within the row
    const float2* H2 = (const float2*)H;
    const float di = dinv[i];
    float2 h = H2[(size_t)i * 64 + fo];
    float2 acc;
    acc.x = h.x * di * di;   // self-loop first
    acc.y = h.y * di * di;
    const int p0 = row_ptr[i], p1 = row_ptr[i + 1];
    for (int base = p0; base < p1; base += 32) {
        int m = p1 - base; if (m > 32) m = 32;
        int sc = 0; float wc = 0.f;
        if (fl < m) { sc = col[base + fl]; wc = dinv[sc] * di; }
        for (int j = 0; j < m; j += 8) {
            int cnt = m - j; if (cnt > 8) cnt = 8;
            float2 hbuf[8]; float wbuf[8];
#pragma unroll
            for (int t = 0; t < 8; ++t) {
                if (t < cnt) {
                    int s = __shfl(sc, j + t, 32);
                    wbuf[t] = __shfl(wc, j + t, 32);
                    hbuf[t] = H2[(size_t)s * 64 + fo];
                }
            }
#pragma unroll
            for (int t = 0; t < 8; ++t) {
                if (t < cnt) {
                    acc.x += hbuf[t].x * wbuf[t];
                    acc.y += hbuf[t].y * wbuf[t];
                }
            }
        }
    }
    float2 bb = ((const float2*)bgl)[fo];
    float2 o;
    o.x = fmaxf(acc.x + bb.x, 0.f);
    o.y = fmaxf(acc.y + bb.y, 0.f);
    ((float2*)Xo)[(size_t)i * 64 + fo] = o;
}

// ---------------- Fused mean pool + MLP head ----------------

__global__ __launch_bounds__(256) void k_poolmlp(const float* __restrict__ X, const int* __restrict__ batch,
                                                 const float* __restrict__ w1, const float* __restrict__ b1,
                                                 const float* __restrict__ w2, const float* __restrict__ b2,
                                                 float* __restrict__ out) {
    __shared__ int s_lo, s_hi;
    __shared__ float red[256];
    __shared__ float xs[128];
    __shared__ float hs[256];
    int g = blockIdx.x, tid = threadIdx.x;
    if (tid == 0) {
        int lo = 0, hi = N_NODES;
        while (lo < hi) { int mid = (lo + hi) >> 1; if (batch[mid] < g) lo = mid + 1; else hi = mid; }
        s_lo = lo;
        int lo2 = lo, hi2 = N_NODES;
        while (lo2 < hi2) { int mid = (lo2 + hi2) >> 1; if (batch[mid] < g + 1) lo2 = mid + 1; else hi2 = mid; }
        s_hi = lo2;
    }
    __syncthreads();
    int lo = s_lo, hi = s_hi;
    int f = tid & 127, half = tid >> 7;
    float acc = 0.f;
    for (int r = lo + half; r < hi; r += 2) acc += X[r * 128 + f];
    red[tid] = acc;
    __syncthreads();
    if (tid < 128) {
        int cnt = hi - lo;
        xs[tid] = (red[tid] + red[tid + 128]) / (float)(cnt > 0 ? cnt : 1);
    }
    __syncthreads();
    float a1 = b1[tid];
#pragma unroll 8
    for (int k = 0; k < 128; ++k) a1 += xs[k] * w1[k * H_DIM + tid];
    hs[tid] = fmaxf(a1, 0.f);
    __syncthreads();
    int j = tid >> 7, t2 = tid & 127;
    float p = hs[t2] * w2[t2 * LABEL_DIM + j] + hs[t2 + 128] * w2[(t2 + 128) * LABEL_DIM + j];
    red[tid] = p;
    __syncthreads();
    for (int s2 = 64; s2 > 0; s2 >>= 1) {
        if (t2 < s2) red[tid] += red[tid + s2];
        __syncthreads();
    }
    if (t2 == 0) out[g * LABEL_DIM + j] = red[tid] + b2[j];
}

// ---------------- launch ----------------

extern "C" void kernel_launch(void* const* d_in, const int* in_sizes, int n_in,
                              void* d_out, int out_size, void* d_ws, size_t ws_size,
                              hipStream_t stream) {
    const float* x   = (const float*)d_in[0];
    const float* Wg  = (const float*)d_in[1];
    const float* bg  = (const float*)d_in[2];
    const float* w1  = (const float*)d_in[3];
    const float* b1  = (const float*)d_in[4];
    const float* w2  = (const float*)d_in[5];
    const float* b2  = (const float*)d_in[6];
    const int* eidx  = (const int*)d_in[7];
    const int* batch = (const int*)d_in[8];
    float* out = (float*)d_out;

    const int* src = eidx;
    const int* dst = eidx + N_EDGES;

    char* ws = (char*)d_ws;
    size_t off = 0;
    float* A = (float*)(ws + off); off += (size_t)N_NODES * FEA_DIM * 4;
    float* B = (float*)(ws + off); off += (size_t)N_NODES * FEA_DIM * 4;
    int*   col = (int*)(ws + off); off += (size_t)N_EDGES * 4;
    int*   row_ptr = (int*)(ws + off); off += 200704;
    int*   cursor  = (int*)(ws + off); off += 200704;
    int*   counts  = (int*)(ws + off); off += 200704;
    float* dinv    = (float*)(ws + off); off += 200704;
    int*   partial = (int*)(ws + off); off += 4096;

    hipMemsetAsync(counts, 0, 200704, stream);
    k_count<<<EDGE_NB, 256, 0, stream>>>(dst, counts);
    k_partial<<<SCAN_NB, 256, 0, stream>>>(counts, partial);
    k_rowptr<<<SCAN_NB, 256, 0, stream>>>(counts, partial, row_ptr, dinv, cursor);
    // gemm layer-0 fused with CSR fill (round-6 proven config)
    k_gemm0_fill<<<GEMM_NB + EDGE_NB, 256, 0, stream>>>(x, Wg, B, src, dst, row_ptr, cursor, col);

    k_agg<<<AGG_NB, 64, 0, stream>>>(B, bg + 0 * FEA_DIM, row_ptr, col, dinv, A);
    for (int l = 1; l < N_LAYER; ++l) {
        k_gemm<<<GEMM_NB, 128, 0, stream>>>(A, Wg + (size_t)l * FEA_DIM * FEA_DIM, B, N_NODES);
        k_agg<<<AGG_NB, 64, 0, stream>>>(B, bg + (size_t)l * FEA_DIM, row_ptr, col, dinv, A);
    }
    k_poolmlp<<<N_GRAPHS, 256, 0, stream>>>(A, batch, w1, b1, w2, b2, out);
}

// Round 10
// 386.397 us; speedup vs baseline: 1.0233x; 1.0149x over previous
//
#include <hip/hip_runtime.h>
#include <hip/hip_bf16.h>

#define N_NODES 50000
#define N_EDGES 600000
#define FEA_DIM 128
#define H_DIM 256
#define N_LAYER 3
#define N_GRAPHS 256
#define LABEL_DIM 2

#define SCAN_NB ((N_NODES + 255) / 256)        // 196
#define GEMM_NB ((N_NODES + 63) / 64)          // 782
#define EDGE_NB ((N_EDGES + 255) / 256)        // 2344 (256-thr kernels)
#define AGG_NB (N_NODES)                       // 50000 one-wave blocks: 2 nodes x 1 half

// ---------------- CSR: degree count ----------------

__global__ __launch_bounds__(256) void k_count(const int* __restrict__ dst, int* __restrict__ counts) {
    int e = blockIdx.x * 256 + threadIdx.x;
    if (e < N_EDGES) atomicAdd(&counts[dst[e]], 1);
}

// ---------------- GEMM body A (round-6 proven): BM=64, BK=32, 256 thr, 4x8 --
// Used ONLY in the fused layer-0 kernel: 256-thr blocks keep the co-scheduled
// CSR-fill blocks at full concurrency (measured 43.6 us with fill fully
// hidden; every 128-thr fused variant exposed the fill).
// Per-output fmac order: k ascending 0..127.

__device__ __forceinline__ void gemm_body256(const float* __restrict__ X, const float* __restrict__ W,
                                             float* __restrict__ H, int M, int tile) {
    __shared__ float a_s[32][68];
    __shared__ float b_s[32][128];
    const int tid = threadIdx.x;
    const int row_g = tid >> 4;
    const int col_g = tid & 15;
    const int row_base = tile * 64;
    float acc[4][8] = {};

    for (int kt = 0; kt < 4; ++kt) {
        const int k0 = kt * 32;
#pragma unroll
        for (int j = 0; j < 2; ++j) {
            int id = tid + j * 256;
            int m = id >> 3;
            int kq = (id & 7) << 2;
            float4 v = make_float4(0.f, 0.f, 0.f, 0.f);
            int gr = row_base + m;
            if (gr < M) v = *(const float4*)(X + gr * 128 + k0 + kq);
            a_s[kq + 0][m] = v.x; a_s[kq + 1][m] = v.y;
            a_s[kq + 2][m] = v.z; a_s[kq + 3][m] = v.w;
        }
#pragma unroll
        for (int j = 0; j < 4; ++j) {
            int id = tid + j * 256;
            int k = id >> 5;
            int n = (id & 31) << 2;
            *(float4*)(&b_s[k][n]) = *(const float4*)(W + (k0 + k) * 128 + n);
        }
        __syncthreads();
#pragma unroll 8
        for (int k = 0; k < 32; ++k) {
            float4 a0 = *(const float4*)(&a_s[k][row_g * 4]);
            float4 b0 = *(const float4*)(&b_s[k][col_g * 4]);
            float4 b1 = *(const float4*)(&b_s[k][64 + col_g * 4]);
            float av[4] = {a0.x, a0.y, a0.z, a0.w};
            float bv[8] = {b0.x, b0.y, b0.z, b0.w, b1.x, b1.y, b1.z, b1.w};
#pragma unroll
            for (int i = 0; i < 4; ++i)
#pragma unroll
                for (int jj = 0; jj < 8; ++jj) acc[i][jj] += av[i] * bv[jj];
        }
        __syncthreads();
    }
#pragma unroll
    for (int i = 0; i < 4; ++i) {
        int gr = row_base + row_g * 4 + i;
        if (gr < M) {
            float4 o0 = {acc[i][0], acc[i][1], acc[i][2], acc[i][3]};
            float4 o1 = {acc[i][4], acc[i][5], acc[i][6], acc[i][7]};
            *(float4*)(H + gr * 128 + col_g * 4) = o0;
            *(float4*)(H + gr * 128 + 64 + col_g * 4) = o1;
        }
    }
}

// Fused: blocks [0, GEMM_NB) run GEMM layer-0 tiles; blocks [GEMM_NB, ...) do
// CSR fill (1 edge/thread, 256 thr — round-6 proven; fill hides under GEMM).
__global__ __launch_bounds__(256) void k_gemm0_fill(const float* __restrict__ X, const float* __restrict__ W,
                                                    float* __restrict__ H,
                                                    const int* __restrict__ src, const int* __restrict__ dst,
                                                    const int* __restrict__ row_ptr, int* __restrict__ cursor,
                                                    int* __restrict__ col) {
    if (blockIdx.x < GEMM_NB) {
        gemm_body256(X, W, H, N_NODES, blockIdx.x);
    } else {
        int e = (blockIdx.x - GEMM_NB) * 256 + threadIdx.x;
        if (e < N_EDGES) {
            int s = src[e], d = dst[e];
            int p = row_ptr[d] + atomicAdd(&cursor[d], 1);
            col[p] = s;
        }
    }
}

// ---------------- GEMM body B (round-7 proven): BM=64, BK=32, 128 thr, 8x8 --
// Plain staging (global->LDS each tile, B-frags read straight from LDS per k).
// VGPR 88, spill-free (round-7/6 WRITE_SIZE parity proves it). Both
// reg-double-buffer attempts (rounds 8-9) spilled at any launch_bounds —
// the compiler won't hold acc(64)+staging(48) in registers for this shape;
// do NOT revisit. 64 fmacs per 64 B LDS reads = 2x the 4x8 intensity.
// Per-output fmac chain: k ascending 0..127 — bitwise identical.

__global__ __launch_bounds__(128) void k_gemm(const float* __restrict__ X, const float* __restrict__ W,
                                              float* __restrict__ H, int M) {
    __shared__ float a_s[32][68];
    __shared__ float b_s[32][128];
    const int tid = threadIdx.x;
    const int row_g = tid >> 4;    // 0..7
    const int col_g = tid & 15;    // 0..15
    const int row_base = blockIdx.x * 64;
    float acc[8][8] = {};

    for (int kt = 0; kt < 4; ++kt) {
        const int k0 = kt * 32;
#pragma unroll
        for (int j = 0; j < 4; ++j) {
            int id = tid + j * 128;        // 0..511
            int m = id >> 3;               // 0..63
            int kq = (id & 7) << 2;
            float4 v = make_float4(0.f, 0.f, 0.f, 0.f);
            int gr = row_base + m;
            if (gr < M) v = *(const float4*)(X + gr * 128 + k0 + kq);
            a_s[kq + 0][m] = v.x; a_s[kq + 1][m] = v.y;
            a_s[kq + 2][m] = v.z; a_s[kq + 3][m] = v.w;
        }
#pragma unroll
        for (int j = 0; j < 8; ++j) {
            int id = tid + j * 128;        // 0..1023
            int k = id >> 5;
            int n = (id & 31) << 2;
            *(float4*)(&b_s[k][n]) = *(const float4*)(W + (k0 + k) * 128 + n);
        }
        __syncthreads();
#pragma unroll 4
        for (int k = 0; k < 32; ++k) {
            float4 a0 = *(const float4*)(&a_s[k][row_g * 8]);
            float4 a1 = *(const float4*)(&a_s[k][row_g * 8 + 4]);
            float4 b0 = *(const float4*)(&b_s[k][col_g * 4]);
            float4 b1 = *(const float4*)(&b_s[k][64 + col_g * 4]);
            float av[8] = {a0.x, a0.y, a0.z, a0.w, a1.x, a1.y, a1.z, a1.w};
            float bv[8] = {b0.x, b0.y, b0.z, b0.w, b1.x, b1.y, b1.z, b1.w};
#pragma unroll
            for (int i = 0; i < 8; ++i)
#pragma unroll
                for (int jj = 0; jj < 8; ++jj) acc[i][jj] += av[i] * bv[jj];
        }
        __syncthreads();
    }
#pragma unroll
    for (int i = 0; i < 8; ++i) {
        int gr = row_base + row_g * 8 + i;
        if (gr < M) {
            float4 o0 = {acc[i][0], acc[i][1], acc[i][2], acc[i][3]};
            float4 o1 = {acc[i][4], acc[i][5], acc[i][6], acc[i][7]};
            *(float4*)(H + gr * 128 + col_g * 4) = o0;
            *(float4*)(H + gr * 128 + 64 + col_g * 4) = o1;
        }
    }
}

// ---------------- CSR build (scan phases) ----------------

__global__ __launch_bounds__(256) void k_partial(const int* __restrict__ counts, int* __restrict__ partial) {
    int g = blockIdx.x * 256 + threadIdx.x;
    int v = (g < N_NODES) ? counts[g] : 0;
#pragma unroll
    for (int off = 32; off > 0; off >>= 1) v += __shfl_down(v, off);
    __shared__ int ws[4];
    int lane = threadIdx.x & 63, wid = threadIdx.x >> 6;
    if (lane == 0) ws[wid] = v;
    __syncthreads();
    if (threadIdx.x == 0) partial[blockIdx.x] = ws[0] + ws[1] + ws[2] + ws[3];
}

__global__ __launch_bounds__(256) void k_rowptr(const int* __restrict__ counts, const int* __restrict__ partial,
                                                int* __restrict__ row_ptr, float* __restrict__ dinv,
                                                int* __restrict__ cursor) {
    __shared__ int sp[256];
    __shared__ int s[256];
    int tid = threadIdx.x;
    sp[tid] = (tid < SCAN_NB) ? partial[tid] : 0;
    __syncthreads();
#pragma unroll
    for (int off = 1; off < 256; off <<= 1) {
        int t = (tid >= off) ? sp[tid - off] : 0;
        __syncthreads();
        sp[tid] += t;
        __syncthreads();
    }
    int block_off = (blockIdx.x == 0) ? 0 : sp[blockIdx.x - 1];

    int g = blockIdx.x * 256 + tid;
    int c = (g < N_NODES) ? counts[g] : 0;
    s[tid] = c;
    __syncthreads();
#pragma unroll
    for (int off = 1; off < 256; off <<= 1) {
        int t = (tid >= off) ? s[tid - off] : 0;
        __syncthreads();
        s[tid] += t;
        __syncthreads();
    }
    if (g < N_NODES) {
        row_ptr[g] = block_off + s[tid] - c;            // exclusive
        dinv[g] = rsqrtf((float)c + 1.0f);              // +1 = self loop
        cursor[g] = 0;
    }
    if (blockIdx.x == 0 && tid == 0) row_ptr[N_NODES] = sp[SCAN_NB - 1];
}

// ---------------- Aggregation: XCD-aware feature split, 1-wave blocks -------
// Round-6 proven (best measured): feature-half = blockIdx&1 (XCD parity),
// unit = 32 lanes = one node's 64-feature half (float2/lane), 1-wave blocks
// (scheduling granularity), batch-of-8 gather prefetch. Per-output fmac
// order: self-loop, then CSR edges strictly ascending — bitwise identical.
// At its latency floor: deeper prefetch (r4), wts stream (r3), plane splits
// (r0-r1), degree sort (r2) all null or negative.

__global__ __launch_bounds__(64) void k_agg(const float* __restrict__ H, const float* __restrict__ bgl,
                                            const int* __restrict__ row_ptr, const int* __restrict__ col,
                                            const float* __restrict__ dinv,
                                            float* __restrict__ Xo) {
    const int b = blockIdx.x;
    const int half = b & 1;                       // feature half (XCD parity)
    const int unit = threadIdx.x >> 5;            // 0..1
    const int fl = threadIdx.x & 31;
    const int i = (b >> 1) * 2 + unit;            // node id (50000 = 25000*2, no tail)
    const int fo = half * 32 + fl;                // float2 index within the row
    const float2* H2 = (const float2*)H;
    const float di = dinv[i];
    float2 h = H2[(size_t)i * 64 + fo];
    float2 acc;
    acc.x = h.x * di * di;   // self-loop first
    acc.y = h.y * di * di;
    const int p0 = row_ptr[i], p1 = row_ptr[i + 1];
    for (int base = p0; base < p1; base += 32) {
        int m = p1 - base; if (m > 32) m = 32;
        int sc = 0; float wc = 0.f;
        if (fl < m) { sc = col[base + fl]; wc = dinv[sc] * di; }
        for (int j = 0; j < m; j += 8) {
            int cnt = m - j; if (cnt > 8) cnt = 8;
            float2 hbuf[8]; float wbuf[8];
#pragma unroll
            for (int t = 0; t < 8; ++t) {
                if (t < cnt) {
                    int s = __shfl(sc, j + t, 32);
                    wbuf[t] = __shfl(wc, j + t, 32);
                    hbuf[t] = H2[(size_t)s * 64 + fo];
                }
            }
#pragma unroll
            for (int t = 0; t < 8; ++t) {
                if (t < cnt) {
                    acc.x += hbuf[t].x * wbuf[t];
                    acc.y += hbuf[t].y * wbuf[t];
                }
            }
        }
    }
    float2 bb = ((const float2*)bgl)[fo];
    float2 o;
    o.x = fmaxf(acc.x + bb.x, 0.f);
    o.y = fmaxf(acc.y + bb.y, 0.f);
    ((float2*)Xo)[(size_t)i * 64 + fo] = o;
}

// ---------------- Fused mean pool + MLP head ----------------

__global__ __launch_bounds__(256) void k_poolmlp(const float* __restrict__ X, const int* __restrict__ batch,
                                                 const float* __restrict__ w1, const float* __restrict__ b1,
                                                 const float* __restrict__ w2, const float* __restrict__ b2,
                                                 float* __restrict__ out) {
    __shared__ int s_lo, s_hi;
    __shared__ float red[256];
    __shared__ float xs[128];
    __shared__ float hs[256];
    int g = blockIdx.x, tid = threadIdx.x;
    if (tid == 0) {
        int lo = 0, hi = N_NODES;
        while (lo < hi) { int mid = (lo + hi) >> 1; if (batch[mid] < g) lo = mid + 1; else hi = mid; }
        s_lo = lo;
        int lo2 = lo, hi2 = N_NODES;
        while (lo2 < hi2) { int mid = (lo2 + hi2) >> 1; if (batch[mid] < g + 1) lo2 = mid + 1; else hi2 = mid; }
        s_hi = lo2;
    }
    __syncthreads();
    int lo = s_lo, hi = s_hi;
    int f = tid & 127, half = tid >> 7;
    float acc = 0.f;
    for (int r = lo + half; r < hi; r += 2) acc += X[r * 128 + f];
    red[tid] = acc;
    __syncthreads();
    if (tid < 128) {
        int cnt = hi - lo;
        xs[tid] = (red[tid] + red[tid + 128]) / (float)(cnt > 0 ? cnt : 1);
    }
    __syncthreads();
    float a1 = b1[tid];
#pragma unroll 8
    for (int k = 0; k < 128; ++k) a1 += xs[k] * w1[k * H_DIM + tid];
    hs[tid] = fmaxf(a1, 0.f);
    __syncthreads();
    int j = tid >> 7, t2 = tid & 127;
    float p = hs[t2] * w2[t2 * LABEL_DIM + j] + hs[t2 + 128] * w2[(t2 + 128) * LABEL_DIM + j];
    red[tid] = p;
    __syncthreads();
    for (int s2 = 64; s2 > 0; s2 >>= 1) {
        if (t2 < s2) red[tid] += red[tid + s2];
        __syncthreads();
    }
    if (t2 == 0) out[g * LABEL_DIM + j] = red[tid] + b2[j];
}

// ---------------- launch ----------------

extern "C" void kernel_launch(void* const* d_in, const int* in_sizes, int n_in,
                              void* d_out, int out_size, void* d_ws, size_t ws_size,
                              hipStream_t stream) {
    const float* x   = (const float*)d_in[0];
    const float* Wg  = (const float*)d_in[1];
    const float* bg  = (const float*)d_in[2];
    const float* w1  = (const float*)d_in[3];
    const float* b1  = (const float*)d_in[4];
    const float* w2  = (const float*)d_in[5];
    const float* b2  = (const float*)d_in[6];
    const int* eidx  = (const int*)d_in[7];
    const int* batch = (const int*)d_in[8];
    float* out = (float*)d_out;

    const int* src = eidx;
    const int* dst = eidx + N_EDGES;

    char* ws = (char*)d_ws;
    size_t off = 0;
    float* A = (float*)(ws + off); off += (size_t)N_NODES * FEA_DIM * 4;
    float* B = (float*)(ws + off); off += (size_t)N_NODES * FEA_DIM * 4;
    int*   col = (int*)(ws + off); off += (size_t)N_EDGES * 4;
    int*   row_ptr = (int*)(ws + off); off += 200704;
    int*   cursor  = (int*)(ws + off); off += 200704;
    int*   counts  = (int*)(ws + off); off += 200704;
    float* dinv    = (float*)(ws + off); off += 200704;
    int*   partial = (int*)(ws + off); off += 4096;

    hipMemsetAsync(counts, 0, 200704, stream);
    k_count<<<EDGE_NB, 256, 0, stream>>>(dst, counts);
    k_partial<<<SCAN_NB, 256, 0, stream>>>(counts, partial);
    k_rowptr<<<SCAN_NB, 256, 0, stream>>>(counts, partial, row_ptr, dinv, cursor);
    // gemm layer-0 fused with CSR fill (round-6 proven config)
    k_gemm0_fill<<<GEMM_NB + EDGE_NB, 256, 0, stream>>>(x, Wg, B, src, dst, row_ptr, cursor, col);

    k_agg<<<AGG_NB, 64, 0, stream>>>(B, bg + 0 * FEA_DIM, row_ptr, col, dinv, A);
    for (int l = 1; l < N_LAYER; ++l) {
        k_gemm<<<GEMM_NB, 128, 0, stream>>>(A, Wg + (size_t)l * FEA_DIM * FEA_DIM, B, N_NODES);
        k_agg<<<AGG_NB, 64, 0, stream>>>(B, bg + (size_t)l * FEA_DIM, row_ptr, col, dinv, A);
    }
    k_poolmlp<<<N_GRAPHS, 256, 0, stream>>>(A, batch, w1, b1, w2, b2, out);
}

// Round 11
// 371.960 us; speedup vs baseline: 1.0631x; 1.0388x over previous
//
#include <hip/hip_runtime.h>
#include <hip/hip_bf16.h>

#define N_NODES 50000
#define N_EDGES 600000
#define FEA_DIM 128
#define H_DIM 256
#define N_LAYER 3
#define N_GRAPHS 256
#define LABEL_DIM 2

#define SCAN_NB ((N_NODES + 255) / 256)        // 196
#define GEMM_NB ((N_NODES + 63) / 64)          // 782  (fused layer-0 tiles, BM=64)
#define GEMM2_NB (((N_NODES + 31) / 32) * 2)   // 3128 (pure gemm: BM=32 x 2 col-halves)
#define EDGE_NB ((N_EDGES + 255) / 256)        // 2344 (256-thr kernels)
#define AGG_NB (N_NODES)                       // 50000 one-wave blocks: 2 nodes x 1 half

// ---------------- CSR: degree count ----------------

__global__ __launch_bounds__(256) void k_count(const int* __restrict__ dst, int* __restrict__ counts) {
    int e = blockIdx.x * 256 + threadIdx.x;
    if (e < N_EDGES) atomicAdd(&counts[dst[e]], 1);
}

// ---------------- GEMM body A (round-6 proven): BM=64, BK=32, 256 thr, 4x8 --
// Used ONLY in the fused layer-0 kernel: 256-thr blocks keep the co-scheduled
// CSR-fill blocks at full concurrency (measured 43.6 us with fill fully
// hidden; every 128-thr fused variant exposed the fill).
// Per-output fmac order: k ascending 0..127.

__device__ __forceinline__ void gemm_body256(const float* __restrict__ X, const float* __restrict__ W,
                                             float* __restrict__ H, int M, int tile) {
    __shared__ float a_s[32][68];
    __shared__ float b_s[32][128];
    const int tid = threadIdx.x;
    const int row_g = tid >> 4;
    const int col_g = tid & 15;
    const int row_base = tile * 64;
    float acc[4][8] = {};

    for (int kt = 0; kt < 4; ++kt) {
        const int k0 = kt * 32;
#pragma unroll
        for (int j = 0; j < 2; ++j) {
            int id = tid + j * 256;
            int m = id >> 3;
            int kq = (id & 7) << 2;
            float4 v = make_float4(0.f, 0.f, 0.f, 0.f);
            int gr = row_base + m;
            if (gr < M) v = *(const float4*)(X + gr * 128 + k0 + kq);
            a_s[kq + 0][m] = v.x; a_s[kq + 1][m] = v.y;
            a_s[kq + 2][m] = v.z; a_s[kq + 3][m] = v.w;
        }
#pragma unroll
        for (int j = 0; j < 4; ++j) {
            int id = tid + j * 256;
            int k = id >> 5;
            int n = (id & 31) << 2;
            *(float4*)(&b_s[k][n]) = *(const float4*)(W + (k0 + k) * 128 + n);
        }
        __syncthreads();
#pragma unroll 8
        for (int k = 0; k < 32; ++k) {
            float4 a0 = *(const float4*)(&a_s[k][row_g * 4]);
            float4 b0 = *(const float4*)(&b_s[k][col_g * 4]);
            float4 b1 = *(const float4*)(&b_s[k][64 + col_g * 4]);
            float av[4] = {a0.x, a0.y, a0.z, a0.w};
            float bv[8] = {b0.x, b0.y, b0.z, b0.w, b1.x, b1.y, b1.z, b1.w};
#pragma unroll
            for (int i = 0; i < 4; ++i)
#pragma unroll
                for (int jj = 0; jj < 8; ++jj) acc[i][jj] += av[i] * bv[jj];
        }
        __syncthreads();
    }
#pragma unroll
    for (int i = 0; i < 4; ++i) {
        int gr = row_base + row_g * 4 + i;
        if (gr < M) {
            float4 o0 = {acc[i][0], acc[i][1], acc[i][2], acc[i][3]};
            float4 o1 = {acc[i][4], acc[i][5], acc[i][6], acc[i][7]};
            *(float4*)(H + gr * 128 + col_g * 4) = o0;
            *(float4*)(H + gr * 128 + 64 + col_g * 4) = o1;
        }
    }
}

// Fused: blocks [0, GEMM_NB) run GEMM layer-0 tiles; blocks [GEMM_NB, ...) do
// CSR fill (1 edge/thread, 256 thr — round-6 proven; fill hides under GEMM).
__global__ __launch_bounds__(256) void k_gemm0_fill(const float* __restrict__ X, const float* __restrict__ W,
                                                    float* __restrict__ H,
                                                    const int* __restrict__ src, const int* __restrict__ dst,
                                                    const int* __restrict__ row_ptr, int* __restrict__ cursor,
                                                    int* __restrict__ col) {
    if (blockIdx.x < GEMM_NB) {
        gemm_body256(X, W, H, N_NODES, blockIdx.x);
    } else {
        int e = (blockIdx.x - GEMM_NB) * 256 + threadIdx.x;
        if (e < N_EDGES) {
            int s = src[e], d = dst[e];
            int p = row_ptr[d] + atomicAdd(&cursor[d], 1);
            col[p] = s;
        }
    }
}

// ---------------- GEMM body B: BM=32, BN=64, BK=32, 64 thr (1 wave), 8x4 ----
// Round-10 diagnosis: pure gemm was GRID-STARVED (782 blocks x 2 waves = 6
// waves/CU avg, Occupancy 10.5%, VALUBusy 26% — fmac bursts uncovered).
// Fix: split N into 2 col-halves and halve BM -> 3128 one-wave blocks; LDS
// 12.8 KB admits 12 blocks/CU = 12 waves/CU, matching the grid's 12.2/CU.
// 1-wave blocks also decouple the barrier (s_barrier with one resident wave
// is ~free — the k_agg round-6 lesson). Thread tile 8 rows x 4 cols, acc 32
// regs, spill-free. W re-read x2 is L2-broadcast (W = 64 KB).
// Per-output fmac chain: k ascending 0..127 — bitwise identical.

__global__ __launch_bounds__(64) void k_gemm(const float* __restrict__ X, const float* __restrict__ W,
                                             float* __restrict__ H, int M) {
    __shared__ float a_s[32][36];
    __shared__ float b_s[32][64];
    const int tid = threadIdx.x;
    const int row_g = tid >> 4;    // 0..3
    const int col_g = tid & 15;    // 0..15
    const int row_base = (blockIdx.x >> 1) * 32;
    const int n_base = (blockIdx.x & 1) * 64;   // col-half (alternates across XCDs)
    float acc[8][4] = {};

    for (int kt = 0; kt < 4; ++kt) {
        const int k0 = kt * 32;
#pragma unroll
        for (int j = 0; j < 4; ++j) {
            int id = tid + j * 64;         // 0..255
            int m = id >> 3;               // 0..31
            int kq = (id & 7) << 2;
            float4 v = make_float4(0.f, 0.f, 0.f, 0.f);
            int gr = row_base + m;
            if (gr < M) v = *(const float4*)(X + gr * 128 + k0 + kq);
            a_s[kq + 0][m] = v.x; a_s[kq + 1][m] = v.y;
            a_s[kq + 2][m] = v.z; a_s[kq + 3][m] = v.w;
        }
#pragma unroll
        for (int j = 0; j < 8; ++j) {
            int id = tid + j * 64;         // 0..511
            int k = id >> 4;               // 0..31
            int n = (id & 15) << 2;        // 0..60
            *(float4*)(&b_s[k][n]) = *(const float4*)(W + (k0 + k) * 128 + n_base + n);
        }
        __syncthreads();
#pragma unroll 4
        for (int k = 0; k < 32; ++k) {
            float4 a0 = *(const float4*)(&a_s[k][row_g * 8]);
            float4 a1 = *(const float4*)(&a_s[k][row_g * 8 + 4]);
            float4 b0 = *(const float4*)(&b_s[k][col_g * 4]);
            float av[8] = {a0.x, a0.y, a0.z, a0.w, a1.x, a1.y, a1.z, a1.w};
            float bv[4] = {b0.x, b0.y, b0.z, b0.w};
#pragma unroll
            for (int i = 0; i < 8; ++i)
#pragma unroll
                for (int jj = 0; jj < 4; ++jj) acc[i][jj] += av[i] * bv[jj];
        }
        __syncthreads();
    }
#pragma unroll
    for (int i = 0; i < 8; ++i) {
        int gr = row_base + row_g * 8 + i;
        if (gr < M) {
            float4 o = {acc[i][0], acc[i][1], acc[i][2], acc[i][3]};
            *(float4*)(H + gr * 128 + n_base + col_g * 4) = o;
        }
    }
}

// ---------------- CSR build (scan phases) ----------------

__global__ __launch_bounds__(256) void k_partial(const int* __restrict__ counts, int* __restrict__ partial) {
    int g = blockIdx.x * 256 + threadIdx.x;
    int v = (g < N_NODES) ? counts[g] : 0;
#pragma unroll
    for (int off = 32; off > 0; off >>= 1) v += __shfl_down(v, off);
    __shared__ int ws[4];
    int lane = threadIdx.x & 63, wid = threadIdx.x >> 6;
    if (lane == 0) ws[wid] = v;
    __syncthreads();
    if (threadIdx.x == 0) partial[blockIdx.x] = ws[0] + ws[1] + ws[2] + ws[3];
}

__global__ __launch_bounds__(256) void k_rowptr(const int* __restrict__ counts, const int* __restrict__ partial,
                                                int* __restrict__ row_ptr, float* __restrict__ dinv,
                                                int* __restrict__ cursor) {
    __shared__ int sp[256];
    __shared__ int s[256];
    int tid = threadIdx.x;
    sp[tid] = (tid < SCAN_NB) ? partial[tid] : 0;
    __syncthreads();
#pragma unroll
    for (int off = 1; off < 256; off <<= 1) {
        int t = (tid >= off) ? sp[tid - off] : 0;
        __syncthreads();
        sp[tid] += t;
        __syncthreads();
    }
    int block_off = (blockIdx.x == 0) ? 0 : sp[blockIdx.x - 1];

    int g = blockIdx.x * 256 + tid;
    int c = (g < N_NODES) ? counts[g] : 0;
    s[tid] = c;
    __syncthreads();
#pragma unroll
    for (int off = 1; off < 256; off <<= 1) {
        int t = (tid >= off) ? s[tid - off] : 0;
        __syncthreads();
        s[tid] += t;
        __syncthreads();
    }
    if (g < N_NODES) {
        row_ptr[g] = block_off + s[tid] - c;            // exclusive
        dinv[g] = rsqrtf((float)c + 1.0f);              // +1 = self loop
        cursor[g] = 0;
    }
    if (blockIdx.x == 0 && tid == 0) row_ptr[N_NODES] = sp[SCAN_NB - 1];
}

// ---------------- Aggregation: XCD-aware feature split, 1-wave blocks -------
// Round-6 proven (best measured): feature-half = blockIdx&1 (XCD parity),
// unit = 32 lanes = one node's 64-feature half (float2/lane), 1-wave blocks
// (scheduling granularity), batch-of-8 gather prefetch. Per-output fmac
// order: self-loop, then CSR edges strictly ascending — bitwise identical.
// At its latency floor: deeper prefetch (r4), wts stream (r3), plane splits
// (r0-r1), degree sort (r2) all null or negative.

__global__ __launch_bounds__(64) void k_agg(const float* __restrict__ H, const float* __restrict__ bgl,
                                            const int* __restrict__ row_ptr, const int* __restrict__ col,
                                            const float* __restrict__ dinv,
                                            float* __restrict__ Xo) {
    const int b = blockIdx.x;
    const int half = b & 1;                       // feature half (XCD parity)
    const int unit = threadIdx.x >> 5;            // 0..1
    const int fl = threadIdx.x & 31;
    const int i = (b >> 1) * 2 + unit;            // node id (50000 = 25000*2, no tail)
    const int fo = half * 32 + fl;                // float2 index within the row
    const float2* H2 = (const float2*)H;
    const float di = dinv[i];
    float2 h = H2[(size_t)i * 64 + fo];
    float2 acc;
    acc.x = h.x * di * di;   // self-loop first
    acc.y = h.y * di * di;
    const int p0 = row_ptr[i], p1 = row_ptr[i + 1];
    for (int base = p0; base < p1; base += 32) {
        int m = p1 - base; if (m > 32) m = 32;
        int sc = 0; float wc = 0.f;
        if (fl < m) { sc = col[base + fl]; wc = dinv[sc] * di; }
        for (int j = 0; j < m; j += 8) {
            int cnt = m - j; if (cnt > 8) cnt = 8;
            float2 hbuf[8]; float wbuf[8];
#pragma unroll
            for (int t = 0; t < 8; ++t) {
                if (t < cnt) {
                    int s = __shfl(sc, j + t, 32);
                    wbuf[t] = __shfl(wc, j + t, 32);
                    hbuf[t] = H2[(size_t)s * 64 + fo];
                }
            }
#pragma unroll
            for (int t = 0; t < 8; ++t) {
                if (t < cnt) {
                    acc.x += hbuf[t].x * wbuf[t];
                    acc.y += hbuf[t].y * wbuf[t];
                }
            }
        }
    }
    float2 bb = ((const float2*)bgl)[fo];
    float2 o;
    o.x = fmaxf(acc.x + bb.x, 0.f);
    o.y = fmaxf(acc.y + bb.y, 0.f);
    ((float2*)Xo)[(size_t)i * 64 + fo] = o;
}

// ---------------- Fused mean pool + MLP head ----------------

__global__ __launch_bounds__(256) void k_poolmlp(const float* __restrict__ X, const int* __restrict__ batch,
                                                 const float* __restrict__ w1, const float* __restrict__ b1,
                                                 const float* __restrict__ w2, const float* __restrict__ b2,
                                                 float* __restrict__ out) {
    __shared__ int s_lo, s_hi;
    __shared__ float red[256];
    __shared__ float xs[128];
    __shared__ float hs[256];
    int g = blockIdx.x, tid = threadIdx.x;
    if (tid == 0) {
        int lo = 0, hi = N_NODES;
        while (lo < hi) { int mid = (lo + hi) >> 1; if (batch[mid] < g) lo = mid + 1; else hi = mid; }
        s_lo = lo;
        int lo2 = lo, hi2 = N_NODES;
        while (lo2 < hi2) { int mid = (lo2 + hi2) >> 1; if (batch[mid] < g + 1) lo2 = mid + 1; else hi2 = mid; }
        s_hi = lo2;
    }
    __syncthreads();
    int lo = s_lo, hi = s_hi;
    int f = tid & 127, half = tid >> 7;
    float acc = 0.f;
    for (int r = lo + half; r < hi; r += 2) acc += X[r * 128 + f];
    red[tid] = acc;
    __syncthreads();
    if (tid < 128) {
        int cnt = hi - lo;
        xs[tid] = (red[tid] + red[tid + 128]) / (float)(cnt > 0 ? cnt : 1);
    }
    __syncthreads();
    float a1 = b1[tid];
#pragma unroll 8
    for (int k = 0; k < 128; ++k) a1 += xs[k] * w1[k * H_DIM + tid];
    hs[tid] = fmaxf(a1, 0.f);
    __syncthreads();
    int j = tid >> 7, t2 = tid & 127;
    float p = hs[t2] * w2[t2 * LABEL_DIM + j] + hs[t2 + 128] * w2[(t2 + 128) * LABEL_DIM + j];
    red[tid] = p;
    __syncthreads();
    for (int s2 = 64; s2 > 0; s2 >>= 1) {
        if (t2 < s2) red[tid] += red[tid + s2];
        __syncthreads();
    }
    if (t2 == 0) out[g * LABEL_DIM + j] = red[tid] + b2[j];
}

// ---------------- launch ----------------

extern "C" void kernel_launch(void* const* d_in, const int* in_sizes, int n_in,
                              void* d_out, int out_size, void* d_ws, size_t ws_size,
                              hipStream_t stream) {
    const float* x   = (const float*)d_in[0];
    const float* Wg  = (const float*)d_in[1];
    const float* bg  = (const float*)d_in[2];
    const float* w1  = (const float*)d_in[3];
    const float* b1  = (const float*)d_in[4];
    const float* w2  = (const float*)d_in[5];
    const float* b2  = (const float*)d_in[6];
    const int* eidx  = (const int*)d_in[7];
    const int* batch = (const int*)d_in[8];
    float* out = (float*)d_out;

    const int* src = eidx;
    const int* dst = eidx + N_EDGES;

    char* ws = (char*)d_ws;
    size_t off = 0;
    float* A = (float*)(ws + off); off += (size_t)N_NODES * FEA_DIM * 4;
    float* B = (float*)(ws + off); off += (size_t)N_NODES * FEA_DIM * 4;
    int*   col = (int*)(ws + off); off += (size_t)N_EDGES * 4;
    int*   row_ptr = (int*)(ws + off); off += 200704;
    int*   cursor  = (int*)(ws + off); off += 200704;
    int*   counts  = (int*)(ws + off); off += 200704;
    float* dinv    = (float*)(ws + off); off += 200704;
    int*   partial = (int*)(ws + off); off += 4096;

    hipMemsetAsync(counts, 0, 200704, stream);
    k_count<<<EDGE_NB, 256, 0, stream>>>(dst, counts);
    k_partial<<<SCAN_NB, 256, 0, stream>>>(counts, partial);
    k_rowptr<<<SCAN_NB, 256, 0, stream>>>(counts, partial, row_ptr, dinv, cursor);
    // gemm layer-0 fused with CSR fill (round-6 proven config)
    k_gemm0_fill<<<GEMM_NB + EDGE_NB, 256, 0, stream>>>(x, Wg, B, src, dst, row_ptr, cursor, col);

    k_agg<<<AGG_NB, 64, 0, stream>>>(B, bg + 0 * FEA_DIM, row_ptr, col, dinv, A);
    for (int l = 1; l < N_LAYER; ++l) {
        k_gemm<<<GEMM2_NB, 64, 0, stream>>>(A, Wg + (size_t)l * FEA_DIM * FEA_DIM, B, N_NODES);
        k_agg<<<AGG_NB, 64, 0, stream>>>(B, bg + (size_t)l * FEA_DIM, row_ptr, col, dinv, A);
    }
    k_poolmlp<<<N_GRAPHS, 256, 0, stream>>>(A, batch, w1, b1, w2, b2, out);
}